// Round 26
// baseline (468.275 us; speedup 1.0000x reference)
//
#include <hip/hip_runtime.h>

// DMMRLoss_52621939310662 — round 26: r25 champion (417.6us) + isolated r18
// delta: conv2 rows as b128 broadcast reads + conv1-out b128 writes
// (strides 552/68), KEEPING scalar L1-hot c2w weight loads (r18's regression
// was attributed to its W2T4 global weight loads — this isolates that claim).
// Everything else byte-identical to r25. Spill canary: VGPR<=72, WRITE ~19KB.

static constexpr int kPS = 433;    // staging plane stride (4-way floor)
static constexpr int kRS = 25;     // staging row stride
static constexpr int kCS = 552;    // conv1-out channel stride (mult 4, 16B rows)
static constexpr int kZS = 68;     // conv1-out z stride (mult 4)

// ---------------- hot kernel: [pack prologue] + conv1+conv2 -> h2[p][k'], pk[p] ----
__global__ __launch_bounds__(256, 4)
void DMMRLoss_52621939310662_kernel(
    const float* __restrict__ src, const float* __restrict__ tgt,
    const float* __restrict__ c1w, const float* __restrict__ c1b,
    const float* __restrict__ c2w, const float* __restrict__ c2b,
    const float* __restrict__ f1w, float* __restrict__ wp4,
    float* __restrict__ h2, float* __restrict__ pk) {
  __shared__ float sBuf[8832];
  __shared__ float sRed[4];
  int p = blockIdx.x;
  int t = threadIdx.x;

  // pack prologue: blocks 0..431 pack wp4[k'][n4] (k' = pos*64+o)
  if (p < 432) {
    int gid = p * 256 + t;           // 432*256 = 1728*64
    int kp = gid >> 6, n4 = gid & 63;
    int o = kp & 63, pos = kp >> 6;
    int korig = o * 27 + pos;
    float4 w;
    w.x = f1w[(size_t)(n4 * 4 + 0) * 1728 + korig];
    w.y = f1w[(size_t)(n4 * 4 + 1) * 1728 + korig];
    w.z = f1w[(size_t)(n4 * 4 + 2) * 1728 + korig];
    w.w = f1w[(size_t)(n4 * 4 + 3) * 1728 + korig];
    ((float4*)wp4)[gid] = w;
  }

  int pd = p / 169; int rem = p - pd * 169; int phh = rem / 13; int pww = rem - phh * 13;
  int z0 = pd * 17, y0 = phh * 17, x0 = pww * 17;

  int wv  = t >> 6;
  int od  = (t >> 3) & 7, oh = t & 7;
  int oc2 = t & 63;

  // stage tgt + count zeros (independent strided loads, shfl reduce)
  float cnt = 0.f;
  for (int idx = t; idx < 4913; idx += 256) {
    int a = idx / 289; int r2 = idx - a * 289; int b = r2 / 17; int c = r2 - b * 17;
    float v = tgt[((size_t)(z0 + a) * 222 + (y0 + b)) * 222 + (x0 + c)];
    sBuf[a * kPS + b * kRS + c] = v;
    if (v == 0.0f) cnt += 1.f;
  }
  #pragma unroll
  for (int o = 32; o > 0; o >>= 1) cnt += __shfl_down(cnt, o, 64);
  if ((t & 63) == 0) sRed[wv] = cnt;
  __syncthreads();                    // staged tgt + counts visible
  float keep = ((sRed[0] + sRed[1] + sRed[2] + sRed[3]) / 4913.0f <= 0.5f) ? 1.0f : 0.0f;
  if (t == 0) pk[p] = keep;

  float acc2[27];
  #pragma unroll
  for (int i = 0; i < 27; i++) acc2[i] = 0.f;

  #pragma unroll 1
  for (int half = 0; half < 2; half++) {
    float acc[4][8];
    #pragma unroll
    for (int i = 0; i < 4; i++)
      #pragma unroll
      for (int j = 0; j < 8; j++) acc[i][j] = 0.f;

    #pragma unroll 1
    for (int ic = 0; ic < 2; ic++) {
      if (half + ic > 0) {            // restage: src (ic1) or tgt (half1/ic0)
        const float* vol = ic ? src : tgt;
        __syncthreads();
        for (int idx = t; idx < 4913; idx += 256) {
          int a = idx / 289; int r2 = idx - a * 289; int b = r2 / 17; int c = r2 - b * 17;
          sBuf[a * kPS + b * kRS + c] =
              vol[((size_t)(z0 + a) * 222 + (y0 + b)) * 222 + (x0 + c)];
        }
        __syncthreads();
      }
      #pragma unroll 1
      for (int td = 0; td < 3; td++) {
        #pragma unroll 1
        for (int th = 0; th < 3; th++) {
          int rbase = (2 * od + td) * kPS + (2 * oh + th) * kRS;
          float a[17];
          #pragma unroll
          for (int x = 0; x < 17; x++) a[x] = sBuf[rbase + x];
          #pragma unroll
          for (int ocr = 0; ocr < 4; ocr++) {
            int oc = half * 16 + wv * 4 + ocr;
            const float* wp = c1w + oc * 54 + ic * 27 + td * 9 + th * 3;
            float w0 = wp[0], w1 = wp[1], w2 = wp[2];
            #pragma unroll
            for (int ow = 0; ow < 8; ow++)
              acc[ocr][ow] += a[2 * ow] * w0 + a[2 * ow + 1] * w1 + a[2 * ow + 2] * w2;
          }
        }
      }
    }
    __syncthreads();                  // conv1 reads of staged patch done
    #pragma unroll
    for (int ocr = 0; ocr < 4; ocr++) {
      int lo = wv * 4 + ocr;
      float b = c1b[half * 16 + lo];
      int base = lo * kCS + od * kZS + oh * 8;       // 16B-aligned
      float4 v0, v1;
      v0.x = fmaxf(acc[ocr][0] + b, 0.f); v0.y = fmaxf(acc[ocr][1] + b, 0.f);
      v0.z = fmaxf(acc[ocr][2] + b, 0.f); v0.w = fmaxf(acc[ocr][3] + b, 0.f);
      v1.x = fmaxf(acc[ocr][4] + b, 0.f); v1.y = fmaxf(acc[ocr][5] + b, 0.f);
      v1.z = fmaxf(acc[ocr][6] + b, 0.f); v1.w = fmaxf(acc[ocr][7] + b, 0.f);
      *(float4*)&sBuf[base]     = v0;                // b128 writes
      *(float4*)&sBuf[base + 4] = v1;
    }
    __syncthreads();

    // conv2: lane = oc2; wave handles local ic = wv*4 + (0..3).
    // Rows read once per (td,th,zo,yo) as 2x b128 broadcast; weights scalar L1-hot.
    #pragma unroll 1
    for (int icr = 0; icr < 4; icr++) {
      int icl = wv * 4 + icr;
      int ic  = half * 16 + icl;
      const float* cbase = sBuf + icl * kCS;
      #pragma unroll 1
      for (int td = 0; td < 3; td++) {
        #pragma unroll 1
        for (int th = 0; th < 3; th++) {
          const float* wp = c2w + oc2 * 864 + ic * 27 + td * 9 + th * 3;
          float w0 = wp[0], w1 = wp[1], w2 = wp[2];
          #pragma unroll
          for (int zo = 0; zo < 3; zo++) {
            #pragma unroll
            for (int yo = 0; yo < 3; yo++) {
              const float4* rp4 =
                  (const float4*)(cbase + (2 * zo + td) * kZS + (2 * yo + th) * 8);
              float4 r0 = rp4[0], r1 = rp4[1];       // broadcast b128
              acc2[zo * 9 + yo * 3 + 0] += r0.x * w0 + r0.y * w1 + r0.z * w2;
              acc2[zo * 9 + yo * 3 + 1] += r0.z * w0 + r0.w * w1 + r1.x * w2;
              acc2[zo * 9 + yo * 3 + 2] += r1.x * w0 + r1.y * w1 + r1.z * w2;
            }
          }
        }
      }
    }
  }
  __syncthreads();
  #pragma unroll
  for (int pos = 0; pos < 27; pos++)
    sBuf[(wv * 27 + pos) * 64 + oc2] = acc2[pos];
  __syncthreads();
  float* h2p = h2 + (size_t)p * 1728;
  for (int idx = t; idx < 1728; idx += 256) {
    int o = idx & 63, pos = idx >> 6;
    float v = sBuf[pos * 64 + o] + sBuf[(27 + pos) * 64 + o] +
              sBuf[(54 + pos) * 64 + o] + sBuf[(81 + pos) * 64 + o];
    h2p[idx] = fmaxf(v + c2b[o], 0.f);       // k' = pos*64+o, coalesced
  }
}

// ---- fc1 GEMM v2 (unchanged): 276 blocks; 4n x 2p per thread ----
static constexpr int kKT = 192;
static constexpr int kTS = 196;

__global__ __launch_bounds__(256, 4)
void dmr26_gemm(const float* __restrict__ h2, const float* __restrict__ wp4,
                const float* __restrict__ f1b, const float* __restrict__ f2w,
                float* __restrict__ part) {
  __shared__ float sT[32 * kTS];
  int b = blockIdx.x;
  int pg = b >> 2, ng = b & 3;
  int p0 = pg * 32;
  int t = threadIdx.x;
  int n4l = t & 15;
  int n4 = ng * 16 + n4l;
  int pgrp = t >> 4;
  int pA = pgrp * 2, pB = pA + 1;

  float acc[4][2];
  #pragma unroll
  for (int j = 0; j < 4; j++) { acc[j][0] = 0.f; acc[j][1] = 0.f; }

  #pragma unroll 1
  for (int kt = 0; kt < 1728; kt += kKT) {
    __syncthreads();
    #pragma unroll
    for (int i = 0; i < 6; i++) {
      int idx = i * 256 + t;
      int pp = idx / 48, kq = idx - pp * 48;
      float4 v = *(const float4*)(h2 + (size_t)(p0 + pp) * 1728 + kt + kq * 4);
      *(float4*)(sT + pp * kTS + kq * 4) = v;
    }
    __syncthreads();
    #pragma unroll 2
    for (int k4 = 0; k4 < kKT / 4; k4++) {
      int kb = kt + k4 * 4;
      float4 w0 = ((const float4*)wp4)[(size_t)(kb + 0) * 64 + n4];
      float4 w1 = ((const float4*)wp4)[(size_t)(kb + 1) * 64 + n4];
      float4 w2 = ((const float4*)wp4)[(size_t)(kb + 2) * 64 + n4];
      float4 w3 = ((const float4*)wp4)[(size_t)(kb + 3) * 64 + n4];
      float4 hA = *(const float4*)(sT + pA * kTS + k4 * 4);
      float4 hB = *(const float4*)(sT + pB * kTS + k4 * 4);
      acc[0][0] += w0.x * hA.x + w1.x * hA.y + w2.x * hA.z + w3.x * hA.w;
      acc[1][0] += w0.y * hA.x + w1.y * hA.y + w2.y * hA.z + w3.y * hA.w;
      acc[2][0] += w0.z * hA.x + w1.z * hA.y + w2.z * hA.z + w3.z * hA.w;
      acc[3][0] += w0.w * hA.x + w1.w * hA.y + w2.w * hA.z + w3.w * hA.w;
      acc[0][1] += w0.x * hB.x + w1.x * hB.y + w2.x * hB.z + w3.x * hB.w;
      acc[1][1] += w0.y * hB.x + w1.y * hB.y + w2.y * hB.z + w3.y * hB.w;
      acc[2][1] += w0.z * hB.x + w1.z * hB.y + w2.z * hB.z + w3.z * hB.w;
      acc[3][1] += w0.w * hB.x + w1.w * hB.y + w2.w * hB.z + w3.w * hB.w;
    }
  }
  float b0 = f1b[n4 * 4 + 0], b1 = f1b[n4 * 4 + 1];
  float b2 = f1b[n4 * 4 + 2], b3 = f1b[n4 * 4 + 3];
  float v0 = f2w[n4 * 4 + 0], v1 = f2w[n4 * 4 + 1];
  float v2 = f2w[n4 * 4 + 2], v3 = f2w[n4 * 4 + 3];
  #pragma unroll
  for (int pp = 0; pp < 2; pp++) {
    float tl = fmaxf(acc[0][pp] + b0, 0.f) * v0 + fmaxf(acc[1][pp] + b1, 0.f) * v1 +
               fmaxf(acc[2][pp] + b2, 0.f) * v2 + fmaxf(acc[3][pp] + b3, 0.f) * v3;
    #pragma unroll
    for (int o = 8; o > 0; o >>= 1) tl += __shfl_down(tl, o, 16);
    if (n4l == 0)
      part[(size_t)(p0 + pA + pp) * 4 + ng] = tl;
  }
}

// ---- final: fc2 bias + tanh + keep-masked mean -> float32 scalar ----
__global__ void dmr26_fin(const float* __restrict__ part, const float* __restrict__ pk,
                          const float* __restrict__ f2b, float* __restrict__ out) {
  __shared__ float s1[256], s2[256];
  int t = threadIdx.x;
  float b0 = f2b[0];
  float a = 0.f, b = 0.f;
  for (int p = t; p < 2197; p += 256) {
    float s = part[4 * p] + part[4 * p + 1] + part[4 * p + 2] + part[4 * p + 3];
    float kv = pk[p];
    a += tanhf(s + b0) * kv;
    b += kv;
  }
  s1[t] = a; s2[t] = b;
  __syncthreads();
  for (int o = 128; o > 0; o >>= 1) {
    if (t < o) { s1[t] += s1[t + o]; s2[t] += s2[t + o]; }
    __syncthreads();
  }
  if (t == 0) out[0] = s1[0] / s2[0];
}

// ---- ws-free fallback: single block, fully fused ----
__global__ __launch_bounds__(256, 2)
void dmr26_solo(const float* __restrict__ src, const float* __restrict__ tgt,
                const float* __restrict__ c1w, const float* __restrict__ c1b,
                const float* __restrict__ c2w, const float* __restrict__ c2b,
                const float* __restrict__ f1w, const float* __restrict__ f1b,
                const float* __restrict__ f2w, const float* __restrict__ f2b,
                float* __restrict__ out) {
  __shared__ float sBuf[8832];
  __shared__ float sH[1728];
  __shared__ float sRed[256];
  __shared__ float sAcc[2];
  int t = threadIdx.x;
  int wv = t >> 6, od = (t >> 3) & 7, oh = t & 7, oc2 = t & 63;
  if (t == 0) { sAcc[0] = 0.f; sAcc[1] = 0.f; }
  for (int p = 0; p < 2197; p++) {
    __syncthreads();
    int pd = p / 169; int rem = p - pd * 169; int phh = rem / 13; int pww = rem - phh * 13;
    int z0 = pd * 17, y0 = phh * 17, x0 = pww * 17;
    float cnt = 0.f;
    for (int idx = t; idx < 4913; idx += 256) {
      int a = idx / 289; int r2 = idx - a * 289; int b = r2 / 17; int c = r2 - b * 17;
      float v = tgt[((size_t)(z0 + a) * 222 + (y0 + b)) * 222 + (x0 + c)];
      sBuf[a * kPS + b * kRS + c] = v;
      if (v == 0.0f) cnt += 1.f;
    }
    sRed[t] = cnt;
    __syncthreads();
    for (int o = 128; o > 0; o >>= 1) {
      if (t < o) sRed[t] += sRed[t + o];
      __syncthreads();
    }
    float keep = (sRed[0] / 4913.0f <= 0.5f) ? 1.0f : 0.0f;
    __syncthreads();
    float acc2[27];
    for (int i = 0; i < 27; i++) acc2[i] = 0.f;
    #pragma unroll 1
    for (int half = 0; half < 2; half++) {
      float acc[4][8];
      for (int i = 0; i < 4; i++)
        for (int j = 0; j < 8; j++) acc[i][j] = 0.f;
      #pragma unroll 1
      for (int ic = 0; ic < 2; ic++) {
        if (half + ic > 0) {
          const float* vol = ic ? src : tgt;
          __syncthreads();
          for (int idx = t; idx < 4913; idx += 256) {
            int a = idx / 289; int r2 = idx - a * 289; int b = r2 / 17; int c = r2 - b * 17;
            sBuf[a * kPS + b * kRS + c] =
                vol[((size_t)(z0 + a) * 222 + (y0 + b)) * 222 + (x0 + c)];
          }
          __syncthreads();
        }
        #pragma unroll 1
        for (int td = 0; td < 3; td++) {
          #pragma unroll 1
          for (int th = 0; th < 3; th++) {
            int rbase = (2 * od + td) * kPS + (2 * oh + th) * kRS;
            float a[17];
            #pragma unroll
            for (int x = 0; x < 17; x++) a[x] = sBuf[rbase + x];
            #pragma unroll
            for (int ocr = 0; ocr < 4; ocr++) {
              int oc = half * 16 + wv * 4 + ocr;
              const float* wp = c1w + oc * 54 + ic * 27 + td * 9 + th * 3;
              float w0 = wp[0], w1 = wp[1], w2 = wp[2];
              #pragma unroll
              for (int ow = 0; ow < 8; ow++)
                acc[ocr][ow] += a[2 * ow] * w0 + a[2 * ow + 1] * w1 + a[2 * ow + 2] * w2;
            }
          }
        }
      }
      __syncthreads();
      #pragma unroll
      for (int ocr = 0; ocr < 4; ocr++) {
        int lo = wv * 4 + ocr;
        float b = c1b[half * 16 + lo];
        int base = lo * kCS + od * kZS + oh * 8;
        #pragma unroll
        for (int ow = 0; ow < 8; ow++)
          sBuf[base + ow] = fmaxf(acc[ocr][ow] + b, 0.f);
      }
      __syncthreads();
      #pragma unroll 1
      for (int icr = 0; icr < 4; icr++) {
        int icl = wv * 4 + icr;
        int ic  = half * 16 + icl;
        const float* cbase = sBuf + icl * kCS;
        #pragma unroll 1
        for (int td = 0; td < 3; td++) {
          #pragma unroll 1
          for (int th = 0; th < 3; th++) {
            const float* wp = c2w + oc2 * 864 + ic * 27 + td * 9 + th * 3;
            float w0 = wp[0], w1 = wp[1], w2 = wp[2];
            #pragma unroll
            for (int zo = 0; zo < 3; zo++) {
              #pragma unroll
              for (int yo = 0; yo < 3; yo++) {
                const float* rp = cbase + (2 * zo + td) * kZS + (2 * yo + th) * 8;
                #pragma unroll
                for (int xo = 0; xo < 3; xo++)
                  acc2[zo * 9 + yo * 3 + xo] +=
                      rp[2 * xo] * w0 + rp[2 * xo + 1] * w1 + rp[2 * xo + 2] * w2;
              }
            }
          }
        }
      }
    }
    __syncthreads();
    #pragma unroll
    for (int pos = 0; pos < 27; pos++)
      sBuf[(wv * 27 + pos) * 64 + oc2] = acc2[pos];
    __syncthreads();
    for (int idx = t; idx < 1728; idx += 256) {
      int o = idx & 63, pos = idx >> 6;
      float v = sBuf[pos * 64 + o] + sBuf[(27 + pos) * 64 + o] +
                sBuf[(54 + pos) * 64 + o] + sBuf[(81 + pos) * 64 + o];
      sH[o * 27 + pos] = fmaxf(v + c2b[o], 0.f);
    }
    __syncthreads();
    float acc1 = 0.f;
    const float* frow = f1w + (size_t)t * 1728;
    #pragma unroll 8
    for (int k = 0; k < 1728; k++) acc1 += sH[k] * frow[k];
    float h = fmaxf(acc1 + f1b[t], 0.f);
    sRed[t] = h * f2w[t];
    __syncthreads();
    for (int o = 128; o > 0; o >>= 1) {
      if (t < o) sRed[t] += sRed[t + o];
      __syncthreads();
    }
    if (t == 0) {
      sAcc[0] += tanhf(sRed[0] + f2b[0]) * keep;
      sAcc[1] += keep;
    }
  }
  __syncthreads();
  if (t == 0) out[0] = sAcc[0] / sAcc[1];
}

extern "C" void kernel_launch(void* const* d_in, const int* in_sizes, int n_in,
                              void* d_out, int out_size, void* d_ws, size_t ws_size,
                              hipStream_t stream) {
  const float* src = (const float*)d_in[0];   // source = moving
  const float* tgt = (const float*)d_in[1];   // target = fixed
  const float* c1w = (const float*)d_in[2];
  const float* c1b = (const float*)d_in[3];
  const float* c2w = (const float*)d_in[4];
  const float* c2b = (const float*)d_in[5];
  const float* f1w = (const float*)d_in[6];
  const float* f1b = (const float*)d_in[7];
  const float* f2w = (const float*)d_in[8];
  const float* f2b = (const float*)d_in[9];
  float* out = (float*)d_out;

  const size_t nWP   = 442368;       // wp4: 1728*64 float4
  const size_t nH2   = (size_t)2208 * 1728;
  const size_t nPart = 2208 * 4;
  const size_t nPk   = 2208;
  if (d_ws && ws_size >= (nWP + nH2 + nPart + nPk) * sizeof(float)) {
    float* wp4  = (float*)d_ws;      // 16B-aligned
    float* h2   = wp4 + nWP;
    float* part = h2 + nH2;
    float* pk   = part + nPart;
    DMMRLoss_52621939310662_kernel<<<2197, 256, 0, stream>>>(
        src, tgt, c1w, c1b, c2w, c2b, f1w, wp4, h2, pk);
    dmr26_gemm<<<276, 256, 0, stream>>>(h2, wp4, f1b, f2w, part);
    dmr26_fin<<<1, 256, 0, stream>>>(part, pk, f2b, out);
  } else {
    dmr26_solo<<<1, 256, 0, stream>>>(
        src, tgt, c1w, c1b, c2w, c2b, f1w, f1b, f2w, f2b, out);
  }
}

// Round 27
// 417.395 us; speedup vs baseline: 1.1219x; 1.1219x over previous
//
#include <hip/hip_runtime.h>

// DMMRLoss_52621939310662 — round 27: restore r25 champion (417.6us) byte-exact.
// r26 isolated conv2-b128 as harmful (+50us): scalar conv2 reads were already
// conflict-free broadcasts that co-issue with VALU; b128 pairs serialize.
// Ledger: every conv-phase restructure regresses (r17,r18,r19/20,r21,r24a,r26);
// banked wins: fc1-GEMM split (r22/23, +18us) and pack-fusion (r25, +3us).

static constexpr int kPS = 433;    // staging plane stride (4-way floor)
static constexpr int kRS = 25;     // staging row stride
static constexpr int kCS = 528;    // conv1-out channel stride
static constexpr int kZS = 66;     // conv1-out z stride (y stride = 8)

// ---------------- hot kernel: [pack prologue] + conv1+conv2 -> h2[p][k'], pk[p] ----
__global__ __launch_bounds__(256, 4)
void DMMRLoss_52621939310662_kernel(
    const float* __restrict__ src, const float* __restrict__ tgt,
    const float* __restrict__ c1w, const float* __restrict__ c1b,
    const float* __restrict__ c2w, const float* __restrict__ c2b,
    const float* __restrict__ f1w, float* __restrict__ wp4,
    float* __restrict__ h2, float* __restrict__ pk) {
  __shared__ float sBuf[8704];
  __shared__ float sRed[4];
  int p = blockIdx.x;
  int t = threadIdx.x;

  // pack prologue: blocks 0..431 pack wp4[k'][n4] (k' = pos*64+o)
  if (p < 432) {
    int gid = p * 256 + t;           // 432*256 = 1728*64
    int kp = gid >> 6, n4 = gid & 63;
    int o = kp & 63, pos = kp >> 6;
    int korig = o * 27 + pos;
    float4 w;
    w.x = f1w[(size_t)(n4 * 4 + 0) * 1728 + korig];
    w.y = f1w[(size_t)(n4 * 4 + 1) * 1728 + korig];
    w.z = f1w[(size_t)(n4 * 4 + 2) * 1728 + korig];
    w.w = f1w[(size_t)(n4 * 4 + 3) * 1728 + korig];
    ((float4*)wp4)[gid] = w;
  }

  int pd = p / 169; int rem = p - pd * 169; int phh = rem / 13; int pww = rem - phh * 13;
  int z0 = pd * 17, y0 = phh * 17, x0 = pww * 17;

  int wv  = t >> 6;
  int od  = (t >> 3) & 7, oh = t & 7;
  int oc2 = t & 63;

  // stage tgt + count zeros (independent strided loads, shfl reduce)
  float cnt = 0.f;
  for (int idx = t; idx < 4913; idx += 256) {
    int a = idx / 289; int r2 = idx - a * 289; int b = r2 / 17; int c = r2 - b * 17;
    float v = tgt[((size_t)(z0 + a) * 222 + (y0 + b)) * 222 + (x0 + c)];
    sBuf[a * kPS + b * kRS + c] = v;
    if (v == 0.0f) cnt += 1.f;
  }
  #pragma unroll
  for (int o = 32; o > 0; o >>= 1) cnt += __shfl_down(cnt, o, 64);
  if ((t & 63) == 0) sRed[wv] = cnt;
  __syncthreads();                    // staged tgt + counts visible
  float keep = ((sRed[0] + sRed[1] + sRed[2] + sRed[3]) / 4913.0f <= 0.5f) ? 1.0f : 0.0f;
  if (t == 0) pk[p] = keep;

  float acc2[27];
  #pragma unroll
  for (int i = 0; i < 27; i++) acc2[i] = 0.f;

  #pragma unroll 1
  for (int half = 0; half < 2; half++) {
    float acc[4][8];
    #pragma unroll
    for (int i = 0; i < 4; i++)
      #pragma unroll
      for (int j = 0; j < 8; j++) acc[i][j] = 0.f;

    #pragma unroll 1
    for (int ic = 0; ic < 2; ic++) {
      if (half + ic > 0) {            // restage: src (ic1) or tgt (half1/ic0)
        const float* vol = ic ? src : tgt;
        __syncthreads();
        for (int idx = t; idx < 4913; idx += 256) {
          int a = idx / 289; int r2 = idx - a * 289; int b = r2 / 17; int c = r2 - b * 17;
          sBuf[a * kPS + b * kRS + c] =
              vol[((size_t)(z0 + a) * 222 + (y0 + b)) * 222 + (x0 + c)];
        }
        __syncthreads();
      }
      #pragma unroll 1
      for (int td = 0; td < 3; td++) {
        #pragma unroll 1
        for (int th = 0; th < 3; th++) {
          int rbase = (2 * od + td) * kPS + (2 * oh + th) * kRS;
          float a[17];
          #pragma unroll
          for (int x = 0; x < 17; x++) a[x] = sBuf[rbase + x];
          #pragma unroll
          for (int ocr = 0; ocr < 4; ocr++) {
            int oc = half * 16 + wv * 4 + ocr;
            const float* wp = c1w + oc * 54 + ic * 27 + td * 9 + th * 3;
            float w0 = wp[0], w1 = wp[1], w2 = wp[2];
            #pragma unroll
            for (int ow = 0; ow < 8; ow++)
              acc[ocr][ow] += a[2 * ow] * w0 + a[2 * ow + 1] * w1 + a[2 * ow + 2] * w2;
          }
        }
      }
    }
    __syncthreads();
    #pragma unroll
    for (int ocr = 0; ocr < 4; ocr++) {
      int lo = wv * 4 + ocr;
      float b = c1b[half * 16 + lo];
      int base = lo * kCS + od * kZS + oh * 8;
      #pragma unroll
      for (int ow = 0; ow < 8; ow++)
        sBuf[base + ow] = fmaxf(acc[ocr][ow] + b, 0.f);
    }
    __syncthreads();

    #pragma unroll 1
    for (int icr = 0; icr < 4; icr++) {
      int icl = wv * 4 + icr;
      int ic  = half * 16 + icl;
      const float* cbase = sBuf + icl * kCS;
      #pragma unroll 1
      for (int td = 0; td < 3; td++) {
        #pragma unroll 1
        for (int th = 0; th < 3; th++) {
          const float* wp = c2w + oc2 * 864 + ic * 27 + td * 9 + th * 3;
          float w0 = wp[0], w1 = wp[1], w2 = wp[2];
          #pragma unroll
          for (int zo = 0; zo < 3; zo++) {
            #pragma unroll
            for (int yo = 0; yo < 3; yo++) {
              const float* rp = cbase + (2 * zo + td) * kZS + (2 * yo + th) * 8;
              #pragma unroll
              for (int xo = 0; xo < 3; xo++)
                acc2[zo * 9 + yo * 3 + xo] +=
                    rp[2 * xo] * w0 + rp[2 * xo + 1] * w1 + rp[2 * xo + 2] * w2;
            }
          }
        }
      }
    }
  }
  __syncthreads();
  #pragma unroll
  for (int pos = 0; pos < 27; pos++)
    sBuf[(wv * 27 + pos) * 64 + oc2] = acc2[pos];
  __syncthreads();
  float* h2p = h2 + (size_t)p * 1728;
  for (int idx = t; idx < 1728; idx += 256) {
    int o = idx & 63, pos = idx >> 6;
    float v = sBuf[pos * 64 + o] + sBuf[(27 + pos) * 64 + o] +
              sBuf[(54 + pos) * 64 + o] + sBuf[(81 + pos) * 64 + o];
    h2p[idx] = fmaxf(v + c2b[o], 0.f);       // k' = pos*64+o, coalesced
  }
}

// ---- fc1 GEMM v2: 276 blocks; 4n x 2p per thread ----
static constexpr int kKT = 192;
static constexpr int kTS = 196;

__global__ __launch_bounds__(256, 4)
void dmr27_gemm(const float* __restrict__ h2, const float* __restrict__ wp4,
                const float* __restrict__ f1b, const float* __restrict__ f2w,
                float* __restrict__ part) {
  __shared__ float sT[32 * kTS];
  int b = blockIdx.x;
  int pg = b >> 2, ng = b & 3;
  int p0 = pg * 32;
  int t = threadIdx.x;
  int n4l = t & 15;
  int n4 = ng * 16 + n4l;
  int pgrp = t >> 4;
  int pA = pgrp * 2, pB = pA + 1;

  float acc[4][2];
  #pragma unroll
  for (int j = 0; j < 4; j++) { acc[j][0] = 0.f; acc[j][1] = 0.f; }

  #pragma unroll 1
  for (int kt = 0; kt < 1728; kt += kKT) {
    __syncthreads();
    #pragma unroll
    for (int i = 0; i < 6; i++) {
      int idx = i * 256 + t;
      int pp = idx / 48, kq = idx - pp * 48;
      float4 v = *(const float4*)(h2 + (size_t)(p0 + pp) * 1728 + kt + kq * 4);
      *(float4*)(sT + pp * kTS + kq * 4) = v;
    }
    __syncthreads();
    #pragma unroll 2
    for (int k4 = 0; k4 < kKT / 4; k4++) {
      int kb = kt + k4 * 4;
      float4 w0 = ((const float4*)wp4)[(size_t)(kb + 0) * 64 + n4];
      float4 w1 = ((const float4*)wp4)[(size_t)(kb + 1) * 64 + n4];
      float4 w2 = ((const float4*)wp4)[(size_t)(kb + 2) * 64 + n4];
      float4 w3 = ((const float4*)wp4)[(size_t)(kb + 3) * 64 + n4];
      float4 hA = *(const float4*)(sT + pA * kTS + k4 * 4);
      float4 hB = *(const float4*)(sT + pB * kTS + k4 * 4);
      acc[0][0] += w0.x * hA.x + w1.x * hA.y + w2.x * hA.z + w3.x * hA.w;
      acc[1][0] += w0.y * hA.x + w1.y * hA.y + w2.y * hA.z + w3.y * hA.w;
      acc[2][0] += w0.z * hA.x + w1.z * hA.y + w2.z * hA.z + w3.z * hA.w;
      acc[3][0] += w0.w * hA.x + w1.w * hA.y + w2.w * hA.z + w3.w * hA.w;
      acc[0][1] += w0.x * hB.x + w1.x * hB.y + w2.x * hB.z + w3.x * hB.w;
      acc[1][1] += w0.y * hB.x + w1.y * hB.y + w2.y * hB.z + w3.y * hB.w;
      acc[2][1] += w0.z * hB.x + w1.z * hB.y + w2.z * hB.z + w3.z * hB.w;
      acc[3][1] += w0.w * hB.x + w1.w * hB.y + w2.w * hB.z + w3.w * hB.w;
    }
  }
  float b0 = f1b[n4 * 4 + 0], b1 = f1b[n4 * 4 + 1];
  float b2 = f1b[n4 * 4 + 2], b3 = f1b[n4 * 4 + 3];
  float v0 = f2w[n4 * 4 + 0], v1 = f2w[n4 * 4 + 1];
  float v2 = f2w[n4 * 4 + 2], v3 = f2w[n4 * 4 + 3];
  #pragma unroll
  for (int pp = 0; pp < 2; pp++) {
    float tl = fmaxf(acc[0][pp] + b0, 0.f) * v0 + fmaxf(acc[1][pp] + b1, 0.f) * v1 +
               fmaxf(acc[2][pp] + b2, 0.f) * v2 + fmaxf(acc[3][pp] + b3, 0.f) * v3;
    #pragma unroll
    for (int o = 8; o > 0; o >>= 1) tl += __shfl_down(tl, o, 16);
    if (n4l == 0)
      part[(size_t)(p0 + pA + pp) * 4 + ng] = tl;
  }
}

// ---- final: fc2 bias + tanh + keep-masked mean -> float32 scalar ----
__global__ void dmr27_fin(const float* __restrict__ part, const float* __restrict__ pk,
                          const float* __restrict__ f2b, float* __restrict__ out) {
  __shared__ float s1[256], s2[256];
  int t = threadIdx.x;
  float b0 = f2b[0];
  float a = 0.f, b = 0.f;
  for (int p = t; p < 2197; p += 256) {
    float s = part[4 * p] + part[4 * p + 1] + part[4 * p + 2] + part[4 * p + 3];
    float kv = pk[p];
    a += tanhf(s + b0) * kv;
    b += kv;
  }
  s1[t] = a; s2[t] = b;
  __syncthreads();
  for (int o = 128; o > 0; o >>= 1) {
    if (t < o) { s1[t] += s1[t + o]; s2[t] += s2[t + o]; }
    __syncthreads();
  }
  if (t == 0) out[0] = s1[0] / s2[0];
}

// ---- ws-free fallback: single block, fully fused ----
__global__ __launch_bounds__(256, 2)
void dmr27_solo(const float* __restrict__ src, const float* __restrict__ tgt,
                const float* __restrict__ c1w, const float* __restrict__ c1b,
                const float* __restrict__ c2w, const float* __restrict__ c2b,
                const float* __restrict__ f1w, const float* __restrict__ f1b,
                const float* __restrict__ f2w, const float* __restrict__ f2b,
                float* __restrict__ out) {
  __shared__ float sBuf[8704];
  __shared__ float sH[1728];
  __shared__ float sRed[256];
  __shared__ float sAcc[2];
  int t = threadIdx.x;
  int wv = t >> 6, od = (t >> 3) & 7, oh = t & 7, oc2 = t & 63;
  if (t == 0) { sAcc[0] = 0.f; sAcc[1] = 0.f; }
  for (int p = 0; p < 2197; p++) {
    __syncthreads();
    int pd = p / 169; int rem = p - pd * 169; int phh = rem / 13; int pww = rem - phh * 13;
    int z0 = pd * 17, y0 = phh * 17, x0 = pww * 17;
    float cnt = 0.f;
    for (int idx = t; idx < 4913; idx += 256) {
      int a = idx / 289; int r2 = idx - a * 289; int b = r2 / 17; int c = r2 - b * 17;
      float v = tgt[((size_t)(z0 + a) * 222 + (y0 + b)) * 222 + (x0 + c)];
      sBuf[a * kPS + b * kRS + c] = v;
      if (v == 0.0f) cnt += 1.f;
    }
    sRed[t] = cnt;
    __syncthreads();
    for (int o = 128; o > 0; o >>= 1) {
      if (t < o) sRed[t] += sRed[t + o];
      __syncthreads();
    }
    float keep = (sRed[0] / 4913.0f <= 0.5f) ? 1.0f : 0.0f;
    __syncthreads();
    float acc2[27];
    for (int i = 0; i < 27; i++) acc2[i] = 0.f;
    #pragma unroll 1
    for (int half = 0; half < 2; half++) {
      float acc[4][8];
      for (int i = 0; i < 4; i++)
        for (int j = 0; j < 8; j++) acc[i][j] = 0.f;
      #pragma unroll 1
      for (int ic = 0; ic < 2; ic++) {
        if (half + ic > 0) {
          const float* vol = ic ? src : tgt;
          __syncthreads();
          for (int idx = t; idx < 4913; idx += 256) {
            int a = idx / 289; int r2 = idx - a * 289; int b = r2 / 17; int c = r2 - b * 17;
            sBuf[a * kPS + b * kRS + c] =
                vol[((size_t)(z0 + a) * 222 + (y0 + b)) * 222 + (x0 + c)];
          }
          __syncthreads();
        }
        #pragma unroll 1
        for (int td = 0; td < 3; td++) {
          #pragma unroll 1
          for (int th = 0; th < 3; th++) {
            int rbase = (2 * od + td) * kPS + (2 * oh + th) * kRS;
            float a[17];
            #pragma unroll
            for (int x = 0; x < 17; x++) a[x] = sBuf[rbase + x];
            #pragma unroll
            for (int ocr = 0; ocr < 4; ocr++) {
              int oc = half * 16 + wv * 4 + ocr;
              const float* wp = c1w + oc * 54 + ic * 27 + td * 9 + th * 3;
              float w0 = wp[0], w1 = wp[1], w2 = wp[2];
              #pragma unroll
              for (int ow = 0; ow < 8; ow++)
                acc[ocr][ow] += a[2 * ow] * w0 + a[2 * ow + 1] * w1 + a[2 * ow + 2] * w2;
            }
          }
        }
      }
      __syncthreads();
      #pragma unroll
      for (int ocr = 0; ocr < 4; ocr++) {
        int lo = wv * 4 + ocr;
        float b = c1b[half * 16 + lo];
        int base = lo * kCS + od * kZS + oh * 8;
        #pragma unroll
        for (int ow = 0; ow < 8; ow++)
          sBuf[base + ow] = fmaxf(acc[ocr][ow] + b, 0.f);
      }
      __syncthreads();
      #pragma unroll 1
      for (int icr = 0; icr < 4; icr++) {
        int icl = wv * 4 + icr;
        int ic  = half * 16 + icl;
        const float* cbase = sBuf + icl * kCS;
        #pragma unroll 1
        for (int td = 0; td < 3; td++) {
          #pragma unroll 1
          for (int th = 0; th < 3; th++) {
            const float* wp = c2w + oc2 * 864 + ic * 27 + td * 9 + th * 3;
            float w0 = wp[0], w1 = wp[1], w2 = wp[2];
            #pragma unroll
            for (int zo = 0; zo < 3; zo++) {
              #pragma unroll
              for (int yo = 0; yo < 3; yo++) {
                const float* rp = cbase + (2 * zo + td) * kZS + (2 * yo + th) * 8;
                #pragma unroll
                for (int xo = 0; xo < 3; xo++)
                  acc2[zo * 9 + yo * 3 + xo] +=
                      rp[2 * xo] * w0 + rp[2 * xo + 1] * w1 + rp[2 * xo + 2] * w2;
              }
            }
          }
        }
      }
    }
    __syncthreads();
    #pragma unroll
    for (int pos = 0; pos < 27; pos++)
      sBuf[(wv * 27 + pos) * 64 + oc2] = acc2[pos];
    __syncthreads();
    for (int idx = t; idx < 1728; idx += 256) {
      int o = idx & 63, pos = idx >> 6;
      float v = sBuf[pos * 64 + o] + sBuf[(27 + pos) * 64 + o] +
                sBuf[(54 + pos) * 64 + o] + sBuf[(81 + pos) * 64 + o];
      sH[o * 27 + pos] = fmaxf(v + c2b[o], 0.f);
    }
    __syncthreads();
    float acc1 = 0.f;
    const float* frow = f1w + (size_t)t * 1728;
    #pragma unroll 8
    for (int k = 0; k < 1728; k++) acc1 += sH[k] * frow[k];
    float h = fmaxf(acc1 + f1b[t], 0.f);
    sRed[t] = h * f2w[t];
    __syncthreads();
    for (int o = 128; o > 0; o >>= 1) {
      if (t < o) sRed[t] += sRed[t + o];
      __syncthreads();
    }
    if (t == 0) {
      sAcc[0] += tanhf(sRed[0] + f2b[0]) * keep;
      sAcc[1] += keep;
    }
  }
  __syncthreads();
  if (t == 0) out[0] = sAcc[0] / sAcc[1];
}

extern "C" void kernel_launch(void* const* d_in, const int* in_sizes, int n_in,
                              void* d_out, int out_size, void* d_ws, size_t ws_size,
                              hipStream_t stream) {
  const float* src = (const float*)d_in[0];   // source = moving
  const float* tgt = (const float*)d_in[1];   // target = fixed
  const float* c1w = (const float*)d_in[2];
  const float* c1b = (const float*)d_in[3];
  const float* c2w = (const float*)d_in[4];
  const float* c2b = (const float*)d_in[5];
  const float* f1w = (const float*)d_in[6];
  const float* f1b = (const float*)d_in[7];
  const float* f2w = (const float*)d_in[8];
  const float* f2b = (const float*)d_in[9];
  float* out = (float*)d_out;

  const size_t nWP   = 442368;       // wp4: 1728*64 float4
  const size_t nH2   = (size_t)2208 * 1728;
  const size_t nPart = 2208 * 4;
  const size_t nPk   = 2208;
  if (d_ws && ws_size >= (nWP + nH2 + nPart + nPk) * sizeof(float)) {
    float* wp4  = (float*)d_ws;      // 16B-aligned
    float* h2   = wp4 + nWP;
    float* part = h2 + nH2;
    float* pk   = part + nPart;
    DMMRLoss_52621939310662_kernel<<<2197, 256, 0, stream>>>(
        src, tgt, c1w, c1b, c2w, c2b, f1w, wp4, h2, pk);
    dmr27_gemm<<<276, 256, 0, stream>>>(h2, wp4, f1b, f2w, part);
    dmr27_fin<<<1, 256, 0, stream>>>(part, pk, f2b, out);
  } else {
    dmr27_solo<<<1, 256, 0, stream>>>(
        src, tgt, c1w, c1b, c2w, c2b, f1w, f1b, f2w, f2b, out);
  }
}